// Round 14
// baseline (7162.646 us; speedup 1.0000x reference)
//
#include <hip/hip_runtime.h>

typedef unsigned short u16;
typedef unsigned int u32;
typedef __attribute__((ext_vector_type(8))) short short8v;
typedef __attribute__((ext_vector_type(4))) float f32x4;
typedef __attribute__((ext_vector_type(4))) unsigned int u32x4;
typedef __attribute__((ext_vector_type(2))) _Float16 f16x2;

#define NB 64
#define NT 256
#define NM 512
#define NH 256

#define K2 2.8853900817779268f   // 2*log2(e)
#define LOG2E 1.4426950408889634f

__device__ __forceinline__ float bf2f(u16 u) {
  union { unsigned i; float f; } c; c.i = ((unsigned)u) << 16; return c.f;
}
__device__ __forceinline__ u16 f2bf(float f) {
  union { float fv; unsigned i; } c; c.fv = f;
  unsigned i = c.i;
  return (u16)((i + 0x7fffu + ((i >> 16) & 1u)) >> 16);
}
__device__ __forceinline__ float bits2f(u32 u) {
  union { unsigned i; float f; } c; c.i = u; return c.f;
}
__device__ __forceinline__ f16x2 u2h2(u32 u) {
  union { u32 i; f16x2 h; } c; c.i = u; return c.h;
}
__device__ __forceinline__ u32 pkrtz(float a, float b) {
  auto h = __builtin_amdgcn_cvt_pkrtz(a, b);
  union { decltype(h) v; u32 i; } c; c.v = h; return c.i;
}
__device__ __forceinline__ float unpk(u32 v, int hi) {
  f16x2 h = u2h2(v);
  return hi ? (float)h.y : (float)h.x;
}
#if __has_builtin(__builtin_amdgcn_fdot2)
__device__ __forceinline__ float FDOT2(f16x2 a, f16x2 b, float c) {
  return __builtin_amdgcn_fdot2(a, b, c, false);
}
#else
__device__ __forceinline__ float FDOT2(f16x2 a, f16x2 b, float c) {
  c = fmaf((float)a.x, (float)b.x, c);
  return fmaf((float)a.y, (float)b.y, c);
}
#endif
__device__ __forceinline__ float tanh_fast(float x) {
  return 1.0f - 2.0f * __builtin_amdgcn_rcpf(1.0f + __builtin_amdgcn_exp2f(K2 * x));
}
__device__ __forceinline__ float sigmoid_fast(float x) {
  return __builtin_amdgcn_rcpf(1.0f + __builtin_amdgcn_exp2f(-LOG2E * x));
}

__global__ void convert_f32_bf16(const float* __restrict__ in, u16* __restrict__ out, int n) {
  int i = blockIdx.x * blockDim.x + threadIdx.x;
  if (i < n) out[i] = f2bf(in[i]);
}

// wdt2[k2*512+m] = pack_f16(Wd_w[m][2k2], Wd_w[m][2k2+1]);  k2 in [0,256)
__global__ __launch_bounds__(256) void pack_wd2(const float* __restrict__ in,
                                                u32* __restrict__ out) {
  int i = blockIdx.x * 256 + threadIdx.x;
  int k2 = i >> 9, m = i & 511;
  out[i] = pkrtz(in[m * 512 + 2 * k2], in[m * 512 + 2 * k2 + 1]);
}
// whht2[k2*1024+r] = pack_f16(Whh[r][2k2], Whh[r][2k2+1]);  k2 in [0,128)
__global__ __launch_bounds__(256) void pack_whh2(const float* __restrict__ in,
                                                 u32* __restrict__ out) {
  int i = blockIdx.x * 256 + threadIdx.x;
  int k2 = i >> 10, r = i & 1023;
  out[i] = pkrtz(in[r * 256 + 2 * k2], in[r * 256 + 2 * k2 + 1]);
}

// y1' = K2 * enc @ Ud^T  (bf16 out, prescaled for exp2-based tanh)
__global__ __launch_bounds__(256) void gemm_y1(const u16* __restrict__ A,
                                               const u16* __restrict__ Bm,
                                               u16* __restrict__ C) {
  const int w = threadIdx.x >> 6;
  const int l = threadIdx.x & 63;
  const int kg = l >> 4;
  const int r16 = l & 15;
  const int rowbase = blockIdx.x * 64 + w * 16;
  const int colbase = blockIdx.y * 64;
  const u16* ap = A + (size_t)(rowbase + r16) * 512 + kg * 8;
  f32x4 acc0 = {0,0,0,0}, acc1 = {0,0,0,0}, acc2 = {0,0,0,0}, acc3 = {0,0,0,0};
  for (int k = 0; k < 512; k += 32) {
    short8v af = *(const short8v*)(ap + k);
    const u16* bp = Bm + (size_t)(colbase + r16) * 512 + kg * 8 + k;
    short8v b0 = *(const short8v*)(bp);
    short8v b1 = *(const short8v*)(bp + 16 * 512);
    short8v b2 = *(const short8v*)(bp + 32 * 512);
    short8v b3 = *(const short8v*)(bp + 48 * 512);
    acc0 = __builtin_amdgcn_mfma_f32_16x16x32_bf16(af, b0, acc0, 0, 0, 0);
    acc1 = __builtin_amdgcn_mfma_f32_16x16x32_bf16(af, b1, acc1, 0, 0, 0);
    acc2 = __builtin_amdgcn_mfma_f32_16x16x32_bf16(af, b2, acc2, 0, 0, 0);
    acc3 = __builtin_amdgcn_mfma_f32_16x16x32_bf16(af, b3, acc3, 0, 0, 0);
  }
  #pragma unroll
  for (int j = 0; j < 4; ++j) {
    int r = rowbase + (l >> 4) * 4 + j;
    C[(size_t)r * 512 + colbase +  0 + r16] = f2bf(K2 * acc0[j]);
    C[(size_t)r * 512 + colbase + 16 + r16] = f2bf(K2 * acc1[j]);
    C[(size_t)r * 512 + colbase + 32 + r16] = f2bf(K2 * acc2[j]);
    C[(size_t)r * 512 + colbase + 48 + r16] = f2bf(K2 * acc3[j]);
  }
}

// w_enc[b,te] = sum_m enc[b,te,m] * wtw[m]
__global__ __launch_bounds__(256) void wenc_kernel(const u16* __restrict__ encbf,
                                                   const float* __restrict__ wtw,
                                                   float* __restrict__ gwenc) {
  int b = blockIdx.x, te = threadIdx.x;
  const u16* ep = encbf + ((size_t)(b * NT + te)) * NM;
  float a = 0.0f;
  for (int c8 = 0; c8 < 64; ++c8) {
    short8v v = *(const short8v*)(ep + c8 * 8);
    #pragma unroll
    for (int jj = 0; jj < 8; ++jj) a = fmaf(bf2f((u16)v[jj]), wtw[c8 * 8 + jj], a);
  }
  gwenc[b * NT + te] = a;
}

// out[b,m] = sum_te betaAcc[b,te] * enc[b,te,m]
__global__ __launch_bounds__(512) void bsum_kernel(const u16* __restrict__ encbf,
                                                   const float* __restrict__ gbeta,
                                                   float* __restrict__ out) {
  __shared__ float bl[NT];
  int b = blockIdx.x, m = threadIdx.x;
  if (m < 256) bl[m] = gbeta[b * NT + m];
  __syncthreads();
  const u16* ep = encbf + (size_t)b * NT * NM + m;
  float a = 0.0f;
  #pragma unroll 8
  for (int te = 0; te < NT; ++te)
    a = fmaf(bf2f(ep[(size_t)te * NM]), bl[te], a);
  out[b * NM + m] = a;
}

// TWO batches per WG (grid=32): B4 loads each weight register once and
// consumes it for BOTH batches -> per-batch L2 weight stream halves.
// Waves 0-7 own batch A, 8-15 own batch B for l_it/softmax/cell.
__global__ void __launch_bounds__(1024) attn_scan(
    const u16* __restrict__ y1bf,    // [B,T,M] prescaled by K2
    const u32* __restrict__ wdt2,    // [256 k2][512 m] f16-pairs along k of (d;s)
    const u32* __restrict__ whht2,   // [128 k2][1024 r] f16-pairs along k of d
    const float* __restrict__ Wd_b,  // [512]
    const float* __restrict__ vd,    // [512]
    const float* __restrict__ wtw,   // [513]
    const float* __restrict__ wtb,   // [1]
    const float* __restrict__ Wih,   // [1024]
    const float* __restrict__ bih,   // [1024]
    const float* __restrict__ bhh,   // [1024]
    const float* __restrict__ yin,   // [B,T]
    const float* __restrict__ gwenc, // [B,256]
    float* __restrict__ gbeta)       // [B,256] sum_t beta
{
  extern __shared__ char ldsraw[];
  u32* gph    = (u32*)ldsraw;              // [2][8][512] f16-pair Whh partials, 32 KiB
  u32* x1ph   = (u32*)(ldsraw + 32768);    // [2][8][256] f16-pair Wd partials, 16 KiB
  float* gact = (float*)(ldsraw + 49152);  // [2][1024] gate activations, 8 KiB

  __shared__ float x1_l2[2][NM];   // [b][j*64 + m>>3] holds x1[m], m = (m>>3)*8 + j
  __shared__ u32 pk_ds[2][256];    // f16 pairs: [0..127]=d, [128..255]=s
  __shared__ float l_sl[2][NT];
  __shared__ float wih_l[1024];
  __shared__ float bb_l[1024];
  __shared__ float wenc_l[2][NT];
  __shared__ float yin_l[2][NT];
  __shared__ float wdb_l[NM];

  const int tid = threadIdx.x;
  const int bA = blockIdx.x * 2;
  const int w = tid >> 6, l = tid & 63;
  const int half = w >> 3;        // 0 = batch A role, 1 = batch B role
  const int wh = w & 7;           // wave index within half
  const int myb = bA + half;

  // ---- one-time init ----
  wih_l[tid] = Wih[tid];
  bb_l[tid] = bih[tid] + bhh[tid];
  if (tid < 512) {
    int bb = tid >> 8, te = tid & 255;
    wenc_l[bb][te] = gwenc[(bA + bb) * NT + te];
    yin_l[bb][te] = yin[(bA + bb) * NT + te];
  }
  if (tid < 512) {
    float wb = Wd_b[tid];
    wdb_l[tid] = wb;
    float v = K2 * wb;             // x1_0 = Wd·0 + b
    x1_l2[0][(tid & 7) * 64 + (tid >> 3)] = v;
    x1_l2[1][(tid & 7) * 64 + (tid >> 3)] = v;
  }
  for (int i = tid; i < 8192; i += 1024) gph[i] = 0;  // Whh·d_{-1} = 0

  float vr[8];
  #pragma unroll
  for (int j = 0; j < 8; ++j) vr[j] = vd[l * 8 + j];
  float sv = 0.0f;
  #pragma unroll
  for (int j = 0; j < 8; ++j) sv += vr[j];
  #pragma unroll
  for (int off = 32; off > 0; off >>= 1) sv += __shfl_xor(sv, off, 64);
  const float Svd = sv;
  const float wtw512 = wtw[NM];
  const float wtb0 = wtb[0];

  const u16* ybase = y1bf + ((size_t)(myb * NT + wh * 32) << 9) + l * 8;

  float s_reg = 0.0f;  // threads 0-255 (A) and 512-767 (B): cell state
  float bacc = 0.0f;   // waves wh>=4: sum_t beta[(wh-4)*64+l] of own batch
  __syncthreads();

  #pragma unroll 1
  for (int t = 0; t < NT; ++t) {
    // ---- B1: l_it — each wave: 32 te of its own batch, y1 streamed from L2.
    // t-rotated row index defeats LICM hoisting into (spilled) tiles.
    {
      float xr[8];
      #pragma unroll
      for (int j = 0; j < 8; ++j) xr[j] = x1_l2[half][j * 64 + l];
      float lout = 0.0f;
      #pragma unroll
      for (int i = 0; i < 32; ++i) {
        const int ii = (i + t) & 31;
        u32x4 V = *(const u32x4*)(ybase + ((size_t)ii << 9));
        float a = 0.0f;
        #pragma unroll
        for (int n = 0; n < 4; ++n) {
          u32 v = V[n];
          float e0 = __builtin_amdgcn_exp2f(xr[2 * n] + bits2f(v << 16));
          a = fmaf(vr[2 * n], __builtin_amdgcn_rcpf(1.0f + e0), a);
          float e1 = __builtin_amdgcn_exp2f(xr[2 * n + 1] + bits2f(v & 0xffff0000u));
          a = fmaf(vr[2 * n + 1], __builtin_amdgcn_rcpf(1.0f + e1), a);
        }
        #pragma unroll
        for (int off = 32; off > 0; off >>= 1) a += __shfl_xor(a, off, 64);
        if (l == ii) lout = Svd - 2.0f * a;
      }
      if (l < 32) l_sl[half][wh * 32 + l] = lout;
    }
    __syncthreads();  // (1) l_sl ready

    // ---- B2: softmax redundantly in all 8 waves of each half ----
    float yt, rden, e0, e1, e2, e3;
    {
      const float* ls = l_sl[half];
      float v0 = ls[l], v1 = ls[64 + l], v2 = ls[128 + l], v3 = ls[192 + l];
      float mx = fmaxf(fmaxf(v0, v1), fmaxf(v2, v3));
      #pragma unroll
      for (int off = 32; off > 0; off >>= 1) mx = fmaxf(mx, __shfl_xor(mx, off, 64));
      e0 = __builtin_amdgcn_exp2f((v0 - mx) * LOG2E);
      e1 = __builtin_amdgcn_exp2f((v1 - mx) * LOG2E);
      e2 = __builtin_amdgcn_exp2f((v2 - mx) * LOG2E);
      e3 = __builtin_amdgcn_exp2f((v3 - mx) * LOG2E);
      float sq = (e0 + e1) + (e2 + e3);
      float nq = fmaf(e0, wenc_l[half][l], fmaf(e1, wenc_l[half][64 + l],
                 fmaf(e2, wenc_l[half][128 + l], e3 * wenc_l[half][192 + l])));
      #pragma unroll
      for (int off = 32; off > 0; off >>= 1) {
        sq += __shfl_xor(sq, off, 64);
        nq += __shfl_xor(nq, off, 64);
      }
      rden = __builtin_amdgcn_rcpf(sq);
      yt = nq * rden + wtw512 * yin_l[half][t] + wtb0;
    }
    if (wh >= 4) {
      float e_own = (wh == 4) ? e0 : (wh == 5) ? e1 : (wh == 6) ? e2 : e3;
      bacc = fmaf(e_own, rden, bacc);
    }

    // ---- B3a: gate activations — each thread 2 rows of its OWN batch ----
    {
      int r0 = tid & 511;
      const u32* gb = gph + half * 4096;
      int hb0 = r0 >> 1, sel0 = r0 & 1;
      int r1 = r0 + 512;
      int hb1 = r1 >> 1, sel1 = r1 & 1;
      float g0 = 0.0f, g1 = 0.0f;
      #pragma unroll
      for (int s = 0; s < 8; ++s) {
        g0 += unpk(gb[s * 512 + hb0], sel0);
        g1 += unpk(gb[s * 512 + hb1], sel1);
      }
      float pre0 = g0 + yt * wih_l[r0] + bb_l[r0];      // r0<512: i or f -> sigmoid
      float pre1 = g1 + yt * wih_l[r1] + bb_l[r1];      // r1: g (r0<256) or o
      gact[half * 1024 + r0] = sigmoid_fast(pre0);
      gact[half * 1024 + r1] = (r0 < 256) ? tanh_fast(pre1) : sigmoid_fast(pre1);
    }
    __syncthreads();  // (2) gact ready

    // ---- B3b: cell update — threads 0-255 (A), 512-767 (B) ----
    if ((tid & 511) < 256) {
      int h = tid & 255;
      const float* ga = gact + half * 1024;
      float gi = ga[h];
      float gf = ga[256 + h];
      float gg = ga[512 + h];
      float go = ga[768 + h];
      float sn = gf * s_reg + gi * gg;
      s_reg = sn;
      float dn = go * tanh_fast(sn);
      float dn1 = __shfl_xor(dn, 1, 64);
      float sn1 = __shfl_xor(sn, 1, 64);
      if ((h & 1) == 0) {
        int hb = h >> 1;
        pk_ds[half][hb] = pkrtz(dn, dn1);
        pk_ds[half][128 + hb] = pkrtz(sn, sn1);
      }
    }
    __syncthreads();  // (3) pk_ds ready

    // ---- B4: all 16 waves; each wave loads weights ONCE, fdot2 for BOTH
    // batches. Job1 Whh: slice=wh k2-range, outhalf=half. Job2 Wd: same split.
    {
      // Job 1: Whh — k2 in [wh*16, wh*16+16), outputs [half*512, +512)
      float a0=0,a1=0,a2=0,a3=0,a4=0,a5=0,a6=0,a7=0;       // batch A
      float b0=0,b1=0,b2=0,b3=0,b4=0,b5=0,b6=0,b7=0;       // batch B
      const u32* base = whht2 + (size_t)(wh * 16) * 1024 + half * 512 + l * 8;
      const u32* pkA = pk_ds[0] + wh * 16;
      const u32* pkB = pk_ds[1] + wh * 16;
      #pragma unroll 4
      for (int kk = 0; kk < 16; ++kk) {
        u32x4 W0 = *(const u32x4*)(base + (size_t)kk * 1024);
        u32x4 W1 = *(const u32x4*)(base + (size_t)kk * 1024 + 4);
        f16x2 dkA = u2h2(pkA[kk]);
        f16x2 dkB = u2h2(pkB[kk]);
        a0 = FDOT2(u2h2(W0[0]), dkA, a0);  b0 = FDOT2(u2h2(W0[0]), dkB, b0);
        a1 = FDOT2(u2h2(W0[1]), dkA, a1);  b1 = FDOT2(u2h2(W0[1]), dkB, b1);
        a2 = FDOT2(u2h2(W0[2]), dkA, a2);  b2 = FDOT2(u2h2(W0[2]), dkB, b2);
        a3 = FDOT2(u2h2(W0[3]), dkA, a3);  b3 = FDOT2(u2h2(W0[3]), dkB, b3);
        a4 = FDOT2(u2h2(W1[0]), dkA, a4);  b4 = FDOT2(u2h2(W1[0]), dkB, b4);
        a5 = FDOT2(u2h2(W1[1]), dkA, a5);  b5 = FDOT2(u2h2(W1[1]), dkB, b5);
        a6 = FDOT2(u2h2(W1[2]), dkA, a6);  b6 = FDOT2(u2h2(W1[2]), dkB, b6);
        a7 = FDOT2(u2h2(W1[3]), dkA, a7);  b7 = FDOT2(u2h2(W1[3]), dkB, b7);
      }
      u32* dA = gph + wh * 512 + half * 256 + l * 4;
      dA[0] = pkrtz(a0, a1); dA[1] = pkrtz(a2, a3);
      dA[2] = pkrtz(a4, a5); dA[3] = pkrtz(a6, a7);
      u32* dB = gph + 4096 + wh * 512 + half * 256 + l * 4;
      dB[0] = pkrtz(b0, b1); dB[1] = pkrtz(b2, b3);
      dB[2] = pkrtz(b4, b5); dB[3] = pkrtz(b6, b7);
    }
    {
      // Job 2: Wd — k2 in [wh*32, wh*32+32), m in [half*256, +256)
      float a0=0,a1=0,a2=0,a3=0;   // batch A (4 m)
      float b0=0,b1=0,b2=0,b3=0;   // batch B
      const u32* base = wdt2 + (size_t)(wh * 32) * 512 + half * 256 + l * 4;
      const u32* pkA = pk_ds[0] + wh * 32;
      const u32* pkB = pk_ds[1] + wh * 32;
      #pragma unroll 8
      for (int kk = 0; kk < 32; ++kk) {
        u32x4 W = *(const u32x4*)(base + (size_t)kk * 512);
        f16x2 dkA = u2h2(pkA[kk]);
        f16x2 dkB = u2h2(pkB[kk]);
        a0 = FDOT2(u2h2(W[0]), dkA, a0);  b0 = FDOT2(u2h2(W[0]), dkB, b0);
        a1 = FDOT2(u2h2(W[1]), dkA, a1);  b1 = FDOT2(u2h2(W[1]), dkB, b1);
        a2 = FDOT2(u2h2(W[2]), dkA, a2);  b2 = FDOT2(u2h2(W[2]), dkB, b2);
        a3 = FDOT2(u2h2(W[3]), dkA, a3);  b3 = FDOT2(u2h2(W[3]), dkB, b3);
      }
      u32* dA = x1ph + wh * 256 + half * 128 + l * 2;
      dA[0] = pkrtz(a0, a1); dA[1] = pkrtz(a2, a3);
      u32* dB = x1ph + 2048 + wh * 256 + half * 128 + l * 2;
      dB[0] = pkrtz(b0, b1); dB[1] = pkrtz(b2, b3);
    }
    __syncthreads();  // (4) x1ph, gph ready

    // ---- B5: assemble x1 for t+1 — 1024 threads = 512 m x 2 batches ----
    {
      int bb = tid >> 9, m = tid & 511;
      int mb = m >> 1, sel = m & 1;
      const u32* xp = x1ph + bb * 2048;
      float s = 0.0f;
      #pragma unroll
      for (int sI = 0; sI < 8; ++sI) s += unpk(xp[sI * 256 + mb], sel);
      x1_l2[bb][(m & 7) * 64 + (m >> 3)] = K2 * (wdb_l[m] + s);
    }
    __syncthreads();  // (5) x1_l2 ready
  }

  if (wh >= 4) gbeta[myb * NT + (wh - 4) * 64 + l] = bacc;
}

extern "C" void kernel_launch(void* const* d_in, const int* in_sizes, int n_in,
                              void* d_out, int out_size, void* d_ws, size_t ws_size,
                              hipStream_t stream) {
  const float* enc  = (const float*)d_in[0];
  const float* yin  = (const float*)d_in[1];
  const float* Wd_w = (const float*)d_in[2];
  const float* Wd_b = (const float*)d_in[3];
  const float* Ud_w = (const float*)d_in[4];
  const float* vd_w = (const float*)d_in[5];
  const float* wt_w = (const float*)d_in[6];
  const float* wt_b = (const float*)d_in[7];
  const float* Wih  = (const float*)d_in[8];
  const float* Whh  = (const float*)d_in[9];
  const float* bih  = (const float*)d_in[10];
  const float* bhh  = (const float*)d_in[11];

  char* ws = (char*)d_ws;
  u16*   y1bf   = (u16*)(ws);                     // 16,777,216
  u16*   encbf  = (u16*)(ws + 16777216);          // 16,777,216
  u16*   udbf   = (u16*)(ws + 33554432);          // 524,288
  u32*   wdt2   = (u32*)(ws + 34078720);          // 524,288
  u32*   whht2  = (u32*)(ws + 34603008);          // 524,288
  float* gwenc  = (float*)(ws + 35127296);        // 65,536
  float* gbeta  = (float*)(ws + 35192832);        // 65,536

  convert_f32_bf16<<<8388608 / 256, 256, 0, stream>>>(enc, encbf, 8388608);
  convert_f32_bf16<<<262144 / 256, 256, 0, stream>>>(Ud_w, udbf, 262144);
  pack_wd2<<<512, 256, 0, stream>>>(Wd_w, wdt2);
  pack_whh2<<<512, 256, 0, stream>>>(Whh, whht2);
  gemm_y1<<<dim3(256, 8), 256, 0, stream>>>(encbf, udbf, y1bf);
  wenc_kernel<<<64, 256, 0, stream>>>(encbf, wt_w, gwenc);

  hipFuncSetAttribute((const void*)attn_scan,
                      hipFuncAttributeMaxDynamicSharedMemorySize, 57344);
  attn_scan<<<32, 1024, 57344, stream>>>(y1bf, wdt2, whht2, Wd_b, vd_w,
                                         wt_w, wt_b, Wih, bih, bhh, yin, gwenc,
                                         gbeta);
  bsum_kernel<<<64, 512, 0, stream>>>(encbf, gbeta, (float*)d_out);
}

// Round 15
// 3964.891 us; speedup vs baseline: 1.8065x; 1.8065x over previous
//
#include <hip/hip_runtime.h>

typedef unsigned short u16;
typedef unsigned int u32;
typedef __attribute__((ext_vector_type(8))) short short8v;
typedef __attribute__((ext_vector_type(4))) float f32x4;
typedef __attribute__((ext_vector_type(4))) unsigned int u32x4;
typedef __attribute__((ext_vector_type(2))) _Float16 f16x2;

#define NB 64
#define NT 256
#define NM 512
#define NH 256

#define K2 2.8853900817779268f   // 2*log2(e)
#define LOG2E 1.4426950408889634f

__device__ __forceinline__ float bf2f(u16 u) {
  union { unsigned i; float f; } c; c.i = ((unsigned)u) << 16; return c.f;
}
__device__ __forceinline__ u16 f2bf(float f) {
  union { float fv; unsigned i; } c; c.fv = f;
  unsigned i = c.i;
  return (u16)((i + 0x7fffu + ((i >> 16) & 1u)) >> 16);
}
__device__ __forceinline__ float bits2f(u32 u) {
  union { unsigned i; float f; } c; c.i = u; return c.f;
}
__device__ __forceinline__ f16x2 u2h2(u32 u) {
  union { u32 i; f16x2 h; } c; c.i = u; return c.h;
}
__device__ __forceinline__ u32 pkrtz(float a, float b) {
  auto h = __builtin_amdgcn_cvt_pkrtz(a, b);
  union { decltype(h) v; u32 i; } c; c.v = h; return c.i;
}
__device__ __forceinline__ float unpk(u32 v, int hi) {
  f16x2 h = u2h2(v);
  return hi ? (float)h.y : (float)h.x;
}
#if __has_builtin(__builtin_amdgcn_fdot2)
__device__ __forceinline__ float FDOT2(f16x2 a, f16x2 b, float c) {
  return __builtin_amdgcn_fdot2(a, b, c, false);
}
#else
__device__ __forceinline__ float FDOT2(f16x2 a, f16x2 b, float c) {
  c = fmaf((float)a.x, (float)b.x, c);
  return fmaf((float)a.y, (float)b.y, c);
}
#endif
__device__ __forceinline__ float tanh_fast(float x) {
  return 1.0f - 2.0f * __builtin_amdgcn_rcpf(1.0f + __builtin_amdgcn_exp2f(K2 * x));
}
__device__ __forceinline__ float sigmoid_fast(float x) {
  return __builtin_amdgcn_rcpf(1.0f + __builtin_amdgcn_exp2f(-LOG2E * x));
}

__global__ void convert_f32_bf16(const float* __restrict__ in, u16* __restrict__ out, int n) {
  int i = blockIdx.x * blockDim.x + threadIdx.x;
  if (i < n) out[i] = f2bf(in[i]);
}

// wdt2[k2*512+m] = pack_f16(Wd_w[m][2k2], Wd_w[m][2k2+1]);  k2 in [0,256)
__global__ __launch_bounds__(256) void pack_wd2(const float* __restrict__ in,
                                                u32* __restrict__ out) {
  int i = blockIdx.x * 256 + threadIdx.x;
  int k2 = i >> 9, m = i & 511;
  out[i] = pkrtz(in[m * 512 + 2 * k2], in[m * 512 + 2 * k2 + 1]);
}
// whht2[k2*1024+r] = pack_f16(Whh[r][2k2], Whh[r][2k2+1]);  k2 in [0,128)
__global__ __launch_bounds__(256) void pack_whh2(const float* __restrict__ in,
                                                 u32* __restrict__ out) {
  int i = blockIdx.x * 256 + threadIdx.x;
  int k2 = i >> 10, r = i & 1023;
  out[i] = pkrtz(in[r * 256 + 2 * k2], in[r * 256 + 2 * k2 + 1]);
}

// y1' = K2 * enc @ Ud^T  (bf16 out, prescaled for exp2-based tanh)
__global__ __launch_bounds__(256) void gemm_y1(const u16* __restrict__ A,
                                               const u16* __restrict__ Bm,
                                               u16* __restrict__ C) {
  const int w = threadIdx.x >> 6;
  const int l = threadIdx.x & 63;
  const int kg = l >> 4;
  const int r16 = l & 15;
  const int rowbase = blockIdx.x * 64 + w * 16;
  const int colbase = blockIdx.y * 64;
  const u16* ap = A + (size_t)(rowbase + r16) * 512 + kg * 8;
  f32x4 acc0 = {0,0,0,0}, acc1 = {0,0,0,0}, acc2 = {0,0,0,0}, acc3 = {0,0,0,0};
  for (int k = 0; k < 512; k += 32) {
    short8v af = *(const short8v*)(ap + k);
    const u16* bp = Bm + (size_t)(colbase + r16) * 512 + kg * 8 + k;
    short8v b0 = *(const short8v*)(bp);
    short8v b1 = *(const short8v*)(bp + 16 * 512);
    short8v b2 = *(const short8v*)(bp + 32 * 512);
    short8v b3 = *(const short8v*)(bp + 48 * 512);
    acc0 = __builtin_amdgcn_mfma_f32_16x16x32_bf16(af, b0, acc0, 0, 0, 0);
    acc1 = __builtin_amdgcn_mfma_f32_16x16x32_bf16(af, b1, acc1, 0, 0, 0);
    acc2 = __builtin_amdgcn_mfma_f32_16x16x32_bf16(af, b2, acc2, 0, 0, 0);
    acc3 = __builtin_amdgcn_mfma_f32_16x16x32_bf16(af, b3, acc3, 0, 0, 0);
  }
  #pragma unroll
  for (int j = 0; j < 4; ++j) {
    int r = rowbase + (l >> 4) * 4 + j;
    C[(size_t)r * 512 + colbase +  0 + r16] = f2bf(K2 * acc0[j]);
    C[(size_t)r * 512 + colbase + 16 + r16] = f2bf(K2 * acc1[j]);
    C[(size_t)r * 512 + colbase + 32 + r16] = f2bf(K2 * acc2[j]);
    C[(size_t)r * 512 + colbase + 48 + r16] = f2bf(K2 * acc3[j]);
  }
}

// w_enc[b,te] = sum_m enc[b,te,m] * wtw[m]
__global__ __launch_bounds__(256) void wenc_kernel(const u16* __restrict__ encbf,
                                                   const float* __restrict__ wtw,
                                                   float* __restrict__ gwenc) {
  int b = blockIdx.x, te = threadIdx.x;
  const u16* ep = encbf + ((size_t)(b * NT + te)) * NM;
  float a = 0.0f;
  for (int c8 = 0; c8 < 64; ++c8) {
    short8v v = *(const short8v*)(ep + c8 * 8);
    #pragma unroll
    for (int jj = 0; jj < 8; ++jj) a = fmaf(bf2f((u16)v[jj]), wtw[c8 * 8 + jj], a);
  }
  gwenc[b * NT + te] = a;
}

// out[b,m] = sum_te betaAcc[b,te] * enc[b,te,m]
__global__ __launch_bounds__(512) void bsum_kernel(const u16* __restrict__ encbf,
                                                   const float* __restrict__ gbeta,
                                                   float* __restrict__ out) {
  __shared__ float bl[NT];
  int b = blockIdx.x, m = threadIdx.x;
  if (m < 256) bl[m] = gbeta[b * NT + m];
  __syncthreads();
  const u16* ep = encbf + (size_t)b * NT * NM + m;
  float a = 0.0f;
  #pragma unroll 8
  for (int te = 0; te < NT; ++te)
    a = fmaf(bf2f(ep[(size_t)te * NM]), bl[te], a);
  out[b * NM + m] = a;
}

// ONE WG per batch (grid=64). Wave-specialized pipeline:
//  P1: waves 0-7 l_it (trans-bound) CONCURRENT with waves 8-15 Whh GEMV
//      (L2-bound) — Whh·d_t is only needed at step t+1's gates, so it runs
//      off the critical path under l_it.
//  P2: softmax (waves 0-7, redundant per wave; 4-7 also accumulate beta)
//  P3: gates+cell fused on waves 0-3 (4 rows/thread; no extra barrier)
//  P4: Wd GEMV on ALL 16 waves (the only serial weight stream)
//  P5: x1 assembly.  4 barriers/step.
__global__ void __launch_bounds__(1024) attn_scan(
    const u16* __restrict__ y1bf,    // [B,T,M] prescaled by K2
    const u32* __restrict__ wdt2,    // [256 k2][512 m] f16-pairs along k of (d;s)
    const u32* __restrict__ whht2,   // [128 k2][1024 r] f16-pairs along k of d
    const float* __restrict__ Wd_b,  // [512]
    const float* __restrict__ vd,    // [512]
    const float* __restrict__ wtw,   // [513]
    const float* __restrict__ wtb,   // [1]
    const float* __restrict__ Wih,   // [1024]
    const float* __restrict__ bih,   // [1024]
    const float* __restrict__ bhh,   // [1024]
    const float* __restrict__ yin,   // [B,T]
    const float* __restrict__ gwenc, // [B,256]
    float* __restrict__ gbeta)       // [B,256] sum_t beta
{
  extern __shared__ char ldsraw[];
  u32* gph  = (u32*)ldsraw;            // [8][512] f16-pair Whh partials, 16 KiB
  u32* x1ph = (u32*)(ldsraw + 16384);  // [16][256] f16-pair Wd partials, 16 KiB

  __shared__ float x1_l2[NM];   // [j][m>>3]: idx (m&7)*64+(m>>3) holds x1[m]
  __shared__ u32 pk_ds[256];    // f16 pairs: [0..127]=d, [128..255]=s
  __shared__ float l_sl[NT];
  __shared__ float wih_l[1024];
  __shared__ float bb_l[1024];
  __shared__ float wenc_l[NT];
  __shared__ float yin_l[NT];
  __shared__ float wdb_l[NM];

  const int tid = threadIdx.x;
  const int b = blockIdx.x;
  const int w = tid >> 6, l = tid & 63;

  // ---- one-time init ----
  wih_l[tid] = Wih[tid];
  bb_l[tid] = bih[tid] + bhh[tid];
  if (tid < 256) {
    wenc_l[tid] = gwenc[b * NT + tid];
    yin_l[tid] = yin[b * NT + tid];
    pk_ds[tid] = 0;                 // d_{-1} = s_{-1} = 0
  }
  if (tid < 512) {
    float wb = Wd_b[tid];
    wdb_l[tid] = wb;
    x1_l2[(tid & 7) * 64 + (tid >> 3)] = K2 * wb;  // x1_0 = Wd·0 + b
  }

  float vr[8];
  #pragma unroll
  for (int j = 0; j < 8; ++j) vr[j] = vd[l * 8 + j];
  float sv = 0.0f;
  #pragma unroll
  for (int j = 0; j < 8; ++j) sv += vr[j];
  #pragma unroll
  for (int off = 32; off > 0; off >>= 1) sv += __shfl_xor(sv, off, 64);
  const float Svd = sv;
  const float wtw512 = wtw[NM];
  const float wtb0 = wtb[0];

  const u16* ybase = y1bf + ((size_t)(b * NT + (w & 7) * 32) << 9) + l * 8;

  float s_reg = 0.0f;  // threads 0-255: cell state c[h]
  float bacc = 0.0f;   // waves 4-7: sum_t beta[(w-4)*64+l]
  __syncthreads();

  #pragma unroll 1
  for (int t = 0; t < NT; ++t) {
    // ---- P1: waves 0-7: l_it (32 te each) | waves 8-15: Whh GEMV ----
    if (w < 8) {
      float xr[8];
      #pragma unroll
      for (int j = 0; j < 8; ++j) xr[j] = x1_l2[j * 64 + l];
      float lout = 0.0f;
      #pragma unroll
      for (int i = 0; i < 32; ++i) {
        const int ii = (i + t) & 31;   // t-rotation defeats LICM/spill
        u32x4 V = *(const u32x4*)(ybase + ((size_t)ii << 9));
        float a = 0.0f;
        #pragma unroll
        for (int n = 0; n < 4; ++n) {
          u32 v = V[n];
          float e0 = __builtin_amdgcn_exp2f(xr[2 * n] + bits2f(v << 16));
          a = fmaf(vr[2 * n], __builtin_amdgcn_rcpf(1.0f + e0), a);
          float e1 = __builtin_amdgcn_exp2f(xr[2 * n + 1] + bits2f(v & 0xffff0000u));
          a = fmaf(vr[2 * n + 1], __builtin_amdgcn_rcpf(1.0f + e1), a);
        }
        #pragma unroll
        for (int off = 32; off > 0; off >>= 1) a += __shfl_xor(a, off, 64);
        if (l == ii) lout = Svd - 2.0f * a;
      }
      if (l < 32) l_sl[w * 32 + l] = lout;
    } else {
      // Whh·d_{t-1} GEMV: slice sl k2-range, all 1024 gate rows
      const int sl = w - 8;
      float a0 = 0, a1 = 0, a2 = 0, a3 = 0, a4 = 0, a5 = 0, a6 = 0, a7 = 0;
      float c0 = 0, c1 = 0, c2 = 0, c3 = 0, c4 = 0, c5 = 0, c6 = 0, c7 = 0;
      const u32* base = whht2 + (size_t)(sl * 16) * 1024 + l * 8;
      const u32* pk = (const u32*)pk_ds + sl * 16;
      #pragma unroll 4
      for (int kk = 0; kk < 16; ++kk) {
        u32x4 Wa0 = *(const u32x4*)(base + (size_t)kk * 1024);
        u32x4 Wa1 = *(const u32x4*)(base + (size_t)kk * 1024 + 4);
        u32x4 Wc0 = *(const u32x4*)(base + (size_t)kk * 1024 + 512);
        u32x4 Wc1 = *(const u32x4*)(base + (size_t)kk * 1024 + 516);
        f16x2 dk = u2h2(pk[kk]);
        a0 = FDOT2(u2h2(Wa0[0]), dk, a0);
        a1 = FDOT2(u2h2(Wa0[1]), dk, a1);
        a2 = FDOT2(u2h2(Wa0[2]), dk, a2);
        a3 = FDOT2(u2h2(Wa0[3]), dk, a3);
        a4 = FDOT2(u2h2(Wa1[0]), dk, a4);
        a5 = FDOT2(u2h2(Wa1[1]), dk, a5);
        a6 = FDOT2(u2h2(Wa1[2]), dk, a6);
        a7 = FDOT2(u2h2(Wa1[3]), dk, a7);
        c0 = FDOT2(u2h2(Wc0[0]), dk, c0);
        c1 = FDOT2(u2h2(Wc0[1]), dk, c1);
        c2 = FDOT2(u2h2(Wc0[2]), dk, c2);
        c3 = FDOT2(u2h2(Wc0[3]), dk, c3);
        c4 = FDOT2(u2h2(Wc1[0]), dk, c4);
        c5 = FDOT2(u2h2(Wc1[1]), dk, c5);
        c6 = FDOT2(u2h2(Wc1[2]), dk, c6);
        c7 = FDOT2(u2h2(Wc1[3]), dk, c7);
      }
      u32* dst = gph + sl * 512 + l * 4;
      dst[0] = pkrtz(a0, a1); dst[1] = pkrtz(a2, a3);
      dst[2] = pkrtz(a4, a5); dst[3] = pkrtz(a6, a7);
      u32* dst2 = gph + sl * 512 + 256 + l * 4;
      dst2[0] = pkrtz(c0, c1); dst2[1] = pkrtz(c2, c3);
      dst2[2] = pkrtz(c4, c5); dst2[3] = pkrtz(c6, c7);
    }
    __syncthreads();  // bar0: l_sl + gph ready

    // ---- P2: softmax (waves 0-7 redundant) + P3: gates+cell (waves 0-3) ----
    if (w < 8) {
      float v0 = l_sl[l], v1 = l_sl[64 + l], v2 = l_sl[128 + l], v3 = l_sl[192 + l];
      float mx = fmaxf(fmaxf(v0, v1), fmaxf(v2, v3));
      #pragma unroll
      for (int off = 32; off > 0; off >>= 1) mx = fmaxf(mx, __shfl_xor(mx, off, 64));
      float e0 = __builtin_amdgcn_exp2f((v0 - mx) * LOG2E);
      float e1 = __builtin_amdgcn_exp2f((v1 - mx) * LOG2E);
      float e2 = __builtin_amdgcn_exp2f((v2 - mx) * LOG2E);
      float e3 = __builtin_amdgcn_exp2f((v3 - mx) * LOG2E);
      float sq = (e0 + e1) + (e2 + e3);
      float nq = fmaf(e0, wenc_l[l], fmaf(e1, wenc_l[64 + l],
                 fmaf(e2, wenc_l[128 + l], e3 * wenc_l[192 + l])));
      #pragma unroll
      for (int off = 32; off > 0; off >>= 1) {
        sq += __shfl_xor(sq, off, 64);
        nq += __shfl_xor(nq, off, 64);
      }
      float rden = __builtin_amdgcn_rcpf(sq);
      float yt = nq * rden + wtw512 * yin_l[t] + wtb0;

      if (tid < 256) {
        // gates + cell fused: thread h owns rows h, 256+h, 512+h, 768+h
        int h = tid, hb = h >> 1, sel = h & 1;
        float g0 = 0.0f, g1 = 0.0f, g2 = 0.0f, g3 = 0.0f;
        #pragma unroll
        for (int s = 0; s < 8; ++s) {
          const u32* gs = gph + s * 512;
          g0 += unpk(gs[hb], sel);
          g1 += unpk(gs[128 + hb], sel);
          g2 += unpk(gs[256 + hb], sel);
          g3 += unpk(gs[384 + hb], sel);
        }
        float gi = sigmoid_fast(g0 + yt * wih_l[h]       + bb_l[h]);
        float gf = sigmoid_fast(g1 + yt * wih_l[256 + h] + bb_l[256 + h]);
        float gg = tanh_fast   (g2 + yt * wih_l[512 + h] + bb_l[512 + h]);
        float go = sigmoid_fast(g3 + yt * wih_l[768 + h] + bb_l[768 + h]);
        float sn = gf * s_reg + gi * gg;
        s_reg = sn;
        float dn = go * tanh_fast(sn);
        float dn1 = __shfl_xor(dn, 1, 64);
        float sn1 = __shfl_xor(sn, 1, 64);
        if (sel == 0) {
          pk_ds[hb] = pkrtz(dn, dn1);
          pk_ds[128 + hb] = pkrtz(sn, sn1);
        }
      } else {
        // beta accumulation: wave w in 4..7 owns te slice (w-4)*64 + l
        float e_own = (w == 4) ? e0 : (w == 5) ? e1 : (w == 6) ? e2 : e3;
        bacc = fmaf(e_own, rden, bacc);
      }
    }
    __syncthreads();  // bar1: pk_ds ready

    // ---- P4: Wd GEMV on ALL 16 waves (k2 slice of 16 each) ----
    {
      float a0 = 0, a1 = 0, a2 = 0, a3 = 0, a4 = 0, a5 = 0, a6 = 0, a7 = 0;
      const u32* base = wdt2 + (size_t)(w * 16) * 512 + l * 8;
      const u32* pk = (const u32*)pk_ds + w * 16;
      #pragma unroll 8
      for (int kk = 0; kk < 16; ++kk) {
        u32x4 W0 = *(const u32x4*)(base + (size_t)kk * 512);
        u32x4 W1 = *(const u32x4*)(base + (size_t)kk * 512 + 4);
        f16x2 dk = u2h2(pk[kk]);
        a0 = FDOT2(u2h2(W0[0]), dk, a0);
        a1 = FDOT2(u2h2(W0[1]), dk, a1);
        a2 = FDOT2(u2h2(W0[2]), dk, a2);
        a3 = FDOT2(u2h2(W0[3]), dk, a3);
        a4 = FDOT2(u2h2(W1[0]), dk, a4);
        a5 = FDOT2(u2h2(W1[1]), dk, a5);
        a6 = FDOT2(u2h2(W1[2]), dk, a6);
        a7 = FDOT2(u2h2(W1[3]), dk, a7);
      }
      u32* dst = x1ph + w * 256 + l * 4;
      dst[0] = pkrtz(a0, a1);
      dst[1] = pkrtz(a2, a3);
      dst[2] = pkrtz(a4, a5);
      dst[3] = pkrtz(a6, a7);
    }
    __syncthreads();  // bar2: x1ph ready

    // ---- P5: assemble x1 for t+1 (threads 0-511, 16 partial slices) ----
    if (tid < 512) {
      int m = tid, mb = m >> 1, sel = m & 1;
      float s = 0.0f;
      #pragma unroll
      for (int sI = 0; sI < 16; ++sI) s += unpk(x1ph[sI * 256 + mb], sel);
      x1_l2[(m & 7) * 64 + (m >> 3)] = K2 * (wdb_l[m] + s);
    }
    __syncthreads();  // bar3: x1_l2 ready
  }

  if (w >= 4 && w < 8) gbeta[b * NT + (w - 4) * 64 + l] = bacc;
}

extern "C" void kernel_launch(void* const* d_in, const int* in_sizes, int n_in,
                              void* d_out, int out_size, void* d_ws, size_t ws_size,
                              hipStream_t stream) {
  const float* enc  = (const float*)d_in[0];
  const float* yin  = (const float*)d_in[1];
  const float* Wd_w = (const float*)d_in[2];
  const float* Wd_b = (const float*)d_in[3];
  const float* Ud_w = (const float*)d_in[4];
  const float* vd_w = (const float*)d_in[5];
  const float* wt_w = (const float*)d_in[6];
  const float* wt_b = (const float*)d_in[7];
  const float* Wih  = (const float*)d_in[8];
  const float* Whh  = (const float*)d_in[9];
  const float* bih  = (const float*)d_in[10];
  const float* bhh  = (const float*)d_in[11];

  char* ws = (char*)d_ws;
  u16*   y1bf   = (u16*)(ws);                     // 16,777,216
  u16*   encbf  = (u16*)(ws + 16777216);          // 16,777,216
  u16*   udbf   = (u16*)(ws + 33554432);          // 524,288
  u32*   wdt2   = (u32*)(ws + 34078720);          // 524,288
  u32*   whht2  = (u32*)(ws + 34603008);          // 524,288
  float* gwenc  = (float*)(ws + 35127296);        // 65,536
  float* gbeta  = (float*)(ws + 35192832);        // 65,536

  convert_f32_bf16<<<8388608 / 256, 256, 0, stream>>>(enc, encbf, 8388608);
  convert_f32_bf16<<<262144 / 256, 256, 0, stream>>>(Ud_w, udbf, 262144);
  pack_wd2<<<512, 256, 0, stream>>>(Wd_w, wdt2);
  pack_whh2<<<512, 256, 0, stream>>>(Whh, whht2);
  gemm_y1<<<dim3(256, 8), 256, 0, stream>>>(encbf, udbf, y1bf);
  wenc_kernel<<<64, 256, 0, stream>>>(encbf, wt_w, gwenc);

  hipFuncSetAttribute((const void*)attn_scan,
                      hipFuncAttributeMaxDynamicSharedMemorySize, 32768);
  attn_scan<<<64, 1024, 32768, stream>>>(y1bf, wdt2, whht2, Wd_b, vd_w,
                                         wt_w, wt_b, Wih, bih, bhh, yin, gwenc,
                                         gbeta);
  bsum_kernel<<<64, 512, 0, stream>>>(encbf, gbeta, (float*)d_out);
}